// Round 17
// baseline (811.622 us; speedup 1.0000x reference)
//
#include <hip/hip_runtime.h>
#include <hip/hip_bf16.h>

typedef unsigned short u16;
typedef short s16x8 __attribute__((ext_vector_type(8)));
typedef float f32x4 __attribute__((ext_vector_type(4)));
typedef __bf16 bf16x8 __attribute__((ext_vector_type(8)));

#define SCALE_F 0.17677669529663687f

// workspace layout (bytes). Adaptive arena; chunking absorbs small ws.
#define OFF_CM    ((size_t)0)                 // 64*12*2401*4 = 7,375,872
#define OFF_WQ    ((size_t)8<<20)             // qkvT  1152*384*2
#define OFF_WP    (OFF_WQ + 884736)           // projT 384*384*2
#define OFF_W1    (OFF_WP + 294912)           // fc1T  1536*384*2
#define OFF_W2    (OFF_W1 + 1179648)          // fc2T  384*1536*2
#define OFF_AWIN  ((size_t)12<<20)            // 77MB: A_win -> (reuse) ln2o
#define OFF_OBUF  ((size_t)90<<20)            // 73.5MB: attention output
#define OFF_X1    ((size_t)164<<20)           // 71.7MB: x1 residual (bf16)
#define OFF_ARENA ((size_t)236<<20)           // qkv chunk / fc1 chunk (adaptive)

#define QKV_FULL  ((size_t)100352*1152*2)     // 231,211,008
#define FC1_FULL  ((size_t)93184*1536*2)      // 286,261,248

static __device__ __forceinline__ u16 f2b(float f) {
    unsigned u = __float_as_uint(f);
    u += 0x7fffu + ((u >> 16) & 1u);
    return (u16)(u >> 16);
}
static __device__ __forceinline__ float b2f(u16 u) {
    return __uint_as_float((unsigned)u << 16);
}

union frag_u { s16x8 s; bf16x8 b; };
static __device__ __forceinline__ bf16x8 tob(s16x8 v) { frag_u u; u.s = v; return u.b; }

static __device__ __forceinline__ void mfma_bf16(f32x4& d, s16x8 a, s16x8 b) {
    asm("v_mfma_f32_16x16x32_bf16 %0, %1, %2, %0" : "+v"(d) : "v"(a), "v"(b));
}

static __device__ __forceinline__ void gload16(const void* g, void* l) {
    __builtin_amdgcn_global_load_lds(
        (const __attribute__((address_space(1))) unsigned int*)g,
        (__attribute__((address_space(3))) unsigned int*)l, 16, 0, 0);
}

// ---- combined mask+bias: CM[wpos][head][r*49+c] ----
__global__ void cm_kernel(const float* __restrict__ am, const float* __restrict__ pm,
                          const float* __restrict__ rpb, const int* __restrict__ ridx,
                          float* __restrict__ cmo)
{
    const int wpos = blockIdx.x, head = blockIdx.y;
    float* o = cmo + ((size_t)wpos*12 + head)*2401;
    const float* a = am + (size_t)wpos*2401;
    const float* p = pm + (size_t)wpos*2401;
    for (int e = threadIdx.x; e < 2401; e += 256)
        o[e] = a[e] + p[e] + rpb[ridx[e]*12 + head];
}

// ---- weight transpose+convert: Wt[n][k] = bf16(W[k][n]) ----
__global__ void wconv_kernel(const float* __restrict__ w, u16* __restrict__ wt,
                             int K, int N)
{
    const int k = blockIdx.x*256 + threadIdx.x;
    const int n = blockIdx.y;
    if (k < K) wt[(size_t)n*K + k] = f2b(w[(size_t)k*N + n]);
}

// ---- layernorm; WINDOWED=1: f32 in + roll/pad/window gather; 0: bf16 in ----
template<int WINDOWED>
__global__ __launch_bounds__(256, 4)
void ln_kernel(const void* __restrict__ xin, const float* __restrict__ g,
               const float* __restrict__ bt, u16* __restrict__ out)
{
    const int lane = threadIdx.x & 63;
    const int row = blockIdx.x*4 + (threadIdx.x >> 6);
    u16* orow = out + (size_t)row*384;
    float v[6];
    if (WINDOWED) {
        const float* x = (const float*)xin;
        const int win = row / 49, n = row - win*49;
        const int wpos = win & 63, b = win >> 6;
        const int n7 = n / 7;
        const int hp = (wpos >> 3)*7 + n7;
        if (hp < 4) {                 // zero-padded rows (wave-uniform)
            #pragma unroll
            for (int j=0;j<6;j++) orow[lane + 64*j] = 0;
            return;
        }
        const int wp = (wpos & 7)*7 + (n - n7*7);
        int h = hp - 1; if (h >= 52) h -= 52;   // (hp-4+3) % 52
        int w = wp + 3; if (w >= 56) w -= 56;
        const float* xr = x + (((size_t)b*52 + h)*56 + w)*384;
        #pragma unroll
        for (int j=0;j<6;j++) v[j] = xr[lane + 64*j];
    } else {
        const u16* xr = (const u16*)xin + (size_t)row*384;
        #pragma unroll
        for (int j=0;j<6;j++) v[j] = b2f(xr[lane + 64*j]);
    }
    float sum = 0.f;
    #pragma unroll
    for (int j=0;j<6;j++) sum += v[j];
    #pragma unroll
    for (int m=1;m<64;m<<=1) sum += __shfl_xor(sum, m);
    const float mean = sum * (1.f/384.f);
    float var = 0.f;
    #pragma unroll
    for (int j=0;j<6;j++){ float d = v[j]-mean; var += d*d; }
    #pragma unroll
    for (int m=1;m<64;m<<=1) var += __shfl_xor(var, m);
    const float rstd = rsqrtf(var*(1.f/384.f) + 1e-5f);
    #pragma unroll
    for (int j=0;j<6;j++){
        const int c = lane + 64*j;
        orow[c] = f2b((v[j]-mean)*rstd*g[c] + bt[c]);
    }
}

// ---- bf16 GEMM, 128x192 tile, BK=64 (2-phase sync, halved barrier count) ----
// 4 waves as 2x2; each wave owns 64 rows x 96 cols (4x6 16x16 frags),
// 2 MFMA k-steps per K-iteration. Same accumulator footprint as R13/R16;
// LDS 80KB -> 2 blocks/CU. 8-chunk XOR swizzle: LDS[r][p] = G[r][p ^ (r&7)];
// store key srow&7 == read key r16&7 (row bits 0-2 come only from r16/srow).
// out[M][N] = A[M][K] @ Bt[N][K]^T + bias    (N % 192 == 0, K % 64 == 0)
// EPI 0: +bias -> bf16, head-blocked qkv layout [win][sel][head][49][32]
// EPI 2: tanh-GELU(+bias) -> bf16
// EPI 1: +bias +x(f32 shortcut) with inverse-window scatter -> bf16 x1
// EPI 3: +bias +x1(bf16) -> f32 d_out
template<int EPI>
__global__ __launch_bounds__(256, 2)
void gemm_kernel(const u16* __restrict__ A, const u16* __restrict__ Bt,
                 const float* __restrict__ bias, void* __restrict__ outp,
                 const void* __restrict__ extra, int M, int N, int K)
{
    (void)M;
    __shared__ u16 Als[2][8192];    // 128 rows x 64
    __shared__ u16 Bls[2][12288];   // 192 rows x 64
    const int tid = threadIdx.x;
    const int lane = tid & 63;
    const int wid = tid >> 6;
    const int wr = wid >> 1, wc = wid & 1;
    const int r16 = lane & 15, kc = lane >> 4;

    // bijective XCD swizzle: contiguous flat ranges -> one XCD (A-panel L2 reuse)
    const int gx = gridDim.x;
    const int nwg = gx * gridDim.y;
    const int flat = blockIdx.y*gx + blockIdx.x;
    const int q8 = nwg >> 3, r8 = nwg & 7;
    const int xcd = flat & 7, idx = flat >> 3;
    const int tile = (xcd < r8 ? xcd*(q8+1) : r8*(q8+1) + (xcd-r8)*q8) + idx;
    const int ty = tile / gx;
    const int m0 = ty*128, n0 = (tile - ty*gx)*192;

    const int srow = tid >> 3, schunk = tid & 7;   // 32 rows per load-group
    const int nk = K >> 6;                          // BK = 64

    // pre-swizzled global source: LDS stays linear, read applies the same XOR
    const u16* Ab = A  + (size_t)(m0 + srow)*K + (schunk ^ (srow & 7))*8;
    const u16* Bb = Bt + (size_t)(n0 + srow)*K + (schunk ^ (srow & 7))*8;
    const size_t rskip = (size_t)32*K;

    #define STAGE(buf, kt_) do { \
        const u16* a_ = Ab + (kt_)*64; \
        const u16* b_ = Bb + (kt_)*64; \
        gload16(a_,           &Als[buf][tid*8]); \
        gload16(a_ +   rskip, &Als[buf][2048  + tid*8]); \
        gload16(a_ + 2*rskip, &Als[buf][4096  + tid*8]); \
        gload16(a_ + 3*rskip, &Als[buf][6144  + tid*8]); \
        gload16(b_,           &Bls[buf][tid*8]); \
        gload16(b_ +   rskip, &Bls[buf][2048  + tid*8]); \
        gload16(b_ + 2*rskip, &Bls[buf][4096  + tid*8]); \
        gload16(b_ + 3*rskip, &Bls[buf][6144  + tid*8]); \
        gload16(b_ + 4*rskip, &Bls[buf][8192  + tid*8]); \
        gload16(b_ + 5*rskip, &Bls[buf][10240 + tid*8]); } while (0)

    STAGE(0, 0);

    f32x4 acc[4][6] = {};
    const int key = r16 & 7;
    for (int kt = 0; kt < nk; ++kt) {
        __syncthreads();
        if (kt + 1 < nk) STAGE((kt + 1) & 1, kt + 1);
        const u16* as = Als[kt & 1];
        const u16* bs = Bls[kt & 1];
        #pragma unroll
        for (int ks = 0; ks < 2; ++ks) {
            const int chunk = ((kc + 4*ks) ^ key)*8;
            s16x8 af[4], bfr[6];
            #pragma unroll
            for (int i=0;i<4;i++)
                af[i]  = *(const s16x8*)&as[(64*wr + 16*i + r16)*64 + chunk];
            #pragma unroll
            for (int j=0;j<6;j++)
                bfr[j] = *(const s16x8*)&bs[(96*wc + 16*j + r16)*64 + chunk];
            #pragma unroll
            for (int i=0;i<4;i++)
                #pragma unroll
                for (int j=0;j<6;j++)
                    mfma_bf16(acc[i][j], af[i], bfr[j]);
        }
    }
    #undef STAGE

    float bj[6];
    #pragma unroll
    for (int j=0;j<6;j++) bj[j] = bias[n0 + 96*wc + 16*j + r16];

    if constexpr (EPI == 0) {
        // head-blocked qkv write: [win][sel(3)][head(12)][49][32]
        u16* out = (u16*)outp;
        int colbase[6];
        #pragma unroll
        for (int j=0;j<6;j++) {
            const int col = n0 + 96*wc + 16*j + r16;
            const int sel = col/384;
            const int head = (col - sel*384) >> 5;
            colbase[j] = (sel*12 + head)*1568 + (col & 31);
        }
        #pragma unroll
        for (int i=0;i<4;i++)
          #pragma unroll
          for (int r=0;r<4;r++) {
            const int row = m0 + 64*wr + 16*i + 4*kc + r;
            const int win = row/49, r49 = row - win*49;
            u16* dst = out + (size_t)win*56448 + (size_t)r49*32;
            #pragma unroll
            for (int j=0;j<6;j++)
                dst[colbase[j]] = f2b(acc[i][j][r] + bj[j]);
          }
    } else if constexpr (EPI == 2) {
        u16* out = (u16*)outp;
        #pragma unroll
        for (int i=0;i<4;i++)
          #pragma unroll
          for (int r=0;r<4;r++) {
            const size_t row = m0 + 64*wr + 16*i + 4*kc + r;
            #pragma unroll
            for (int j=0;j<6;j++) {
                const int col = n0 + 96*wc + 16*j + r16;
                float v = acc[i][j][r] + bj[j];
                const float u2 = v*(0.79788456f + 0.035677408f*v*v);
                v = v / (1.f + __expf(-2.f*u2));
                out[row*(size_t)N + col] = f2b(v);
            }
          }
    } else if constexpr (EPI == 3) {
        float* out = (float*)outp;
        const u16* ex = (const u16*)extra;
        #pragma unroll
        for (int i=0;i<4;i++)
          #pragma unroll
          for (int r=0;r<4;r++) {
            const size_t row = m0 + 64*wr + 16*i + 4*kc + r;
            #pragma unroll
            for (int j=0;j<6;j++) {
                const int col = n0 + 96*wc + 16*j + r16;
                out[row*(size_t)N + col] = b2f(ex[row*(size_t)N + col]) + acc[i][j][r] + bj[j];
            }
          }
    } else { // EPI == 1: x1(bf16) = x(f32) + proj_out, inverse-window scatter
        u16* out = (u16*)outp;
        const float* ex = (const float*)extra;
        #pragma unroll
        for (int i=0;i<4;i++)
          #pragma unroll
          for (int r=0;r<4;r++) {
            const int row = m0 + 64*wr + 16*i + 4*kc + r;
            const int win = row / 49, n = row - win*49;
            const int wpos = win & 63, b = win >> 6;
            const int n7 = n / 7;
            const int hp = (wpos >> 3)*7 + n7;
            if (hp < 4) continue;               // dropped padded rows
            const int wp = (wpos & 7)*7 + (n - n7*7);
            int h = hp + 2; if (h >= 52) h -= 52;   // (hp-4+6) % 52
            int w = wp + 6; if (w >= 56) w -= 56;
            const size_t base = (((size_t)b*52 + h)*56 + w)*384;
            #pragma unroll
            for (int j=0;j<6;j++) {
                const int col = n0 + 96*wc + 16*j + r16;
                out[base + col] = f2b(ex[base + col] + acc[i][j][r] + bj[j]);
            }
          }
    }
}

// ---- MFMA attention v2 (R7/R9-proven) on head-blocked qkv layout ----
// qkv arena: [win][sel(3)][head(12)][49][32] bf16 — rows are 64B, dense.
// 4 blocks/CU (LDS 4x38.9KB=155.6 <= 160KB; VGPR 88 — ran correct in R15/R16).
__global__ __launch_bounds__(256, 4)
void attn_mfma2(const u16* __restrict__ qkvc, const float* __restrict__ cm,
                u16* __restrict__ o, int win_base)
{
    __shared__ float Sls[4][2432];    // 9728 B per wave
    const int tid = threadIdx.x, lane = tid & 63, wv = tid >> 6;
    const int u = blockIdx.x*4 + wv;
    const int wloc = u / 12, head = u - wloc*12;
    const int wglob = win_base + wloc;
    const int wpos = wglob & 63;
    const int r16 = lane & 15, kc = lane >> 4;
    const u16* bq = qkvc + ((size_t)(wloc*3 + 0)*12 + head)*1568;
    const u16* bk = qkvc + ((size_t)(wloc*3 + 1)*12 + head)*1568;
    const u16* bv = qkvc + ((size_t)(wloc*3 + 2)*12 + head)*1568;

    // Q,K fragments (rows padded with zeros beyond 48)
    bf16x8 qf[4], kf[4];
    #pragma unroll
    for (int i=0;i<4;i++) {
        const int row = 16*i + r16;
        s16x8 qv = {}, kv = {};
        if (row < 49) {
            qv = *(const s16x8*)&bq[row*32 + kc*8];
            kv = *(const s16x8*)&bk[row*32 + kc*8];
        }
        qf[i] = tob(qv); kf[i] = tob(kv);
    }

    // S = Q@K^T, scaled + mask, into LDS f32
    float* sw = Sls[wv];
    const float* cmb = cm + ((size_t)wpos*12 + head)*2401;
    #pragma unroll
    for (int i=0;i<4;i++)
      #pragma unroll
      for (int j=0;j<4;j++) {
        f32x4 s = {};
        s = __builtin_amdgcn_mfma_f32_16x16x32_bf16(qf[i], kf[j], s, 0, 0, 0);
        #pragma unroll
        for (int r=0;r<4;r++) {
            const int row = 16*i + 4*kc + r;
            const int col = 16*j + r16;
            if (row < 49 && col < 49)
                sw[row*49 + col] = s[r]*SCALE_F + cmb[row*49 + col];
        }
      }
    __syncthreads();

    // softmax: proven scalar pattern — lane r owns row r, all fp32
    float e[49]; float inv = 0.f;
    const int r = lane;
    if (r < 49) {
        #pragma unroll
        for (int c=0;c<49;c++) e[c] = sw[r*49 + c];
        float mx = -1e30f;
        #pragma unroll
        for (int c=0;c<49;c++) mx = fmaxf(mx, e[c]);
        float sm = 0.f;
        #pragma unroll
        for (int c=0;c<49;c++){ e[c] = __expf(e[c]-mx); sm += e[c]; }
        inv = 1.f/sm;
    }
    __syncthreads();   // all S reads complete before the P overlay is written

    // P (bf16, stride 72, cols 49..63 zeroed) overlays the S region
    u16* pw = (u16*)sw;
    if (r < 49) {
        #pragma unroll
        for (int w8 = 0; w8 < 8; ++w8) {
            s16x8 pk = {};
            #pragma unroll
            for (int jj=0;jj<8;jj++) {
                const int c = w8*8 + jj;
                if (c < 49) pk[jj] = (short)f2b(e[c]*inv);
            }
            *(s16x8*)&pw[r*72 + w8*8] = pk;
        }
    }
    __syncthreads();

    // V in B-fragment layout (k>48 clamped to row 0; multiplied by P==0)
    bf16x8 vf[2][2];
    #pragma unroll
    for (int kk=0;kk<2;kk++)
      #pragma unroll
      for (int jn=0;jn<2;jn++) {
        s16x8 vv;
        #pragma unroll
        for (int jj=0;jj<8;jj++) {
            int k = 32*kk + 8*kc + jj;
            if (k > 48) k = 0;
            vv[jj] = (short)bv[k*32 + 16*jn + r16];
        }
        vf[kk][jn] = tob(vv);
      }

    // O = P @ V
    f32x4 oa[4][2] = {};
    #pragma unroll
    for (int i=0;i<4;i++)
      #pragma unroll
      for (int kk=0;kk<2;kk++) {
        const bf16x8 pa = tob(*(const s16x8*)&pw[(16*i + r16)*72 + 32*kk + kc*8]);
        #pragma unroll
        for (int jn=0;jn<2;jn++)
            oa[i][jn] = __builtin_amdgcn_mfma_f32_16x16x32_bf16(pa, vf[kk][jn], oa[i][jn], 0, 0, 0);
      }

    #pragma unroll
    for (int i=0;i<4;i++)
      #pragma unroll
      for (int rr=0;rr<4;rr++) {
        const int row = 16*i + 4*kc + rr;
        if (row < 49) {
          #pragma unroll
          for (int jn=0;jn<2;jn++)
            o[(size_t)(wglob*49 + row)*384 + head*32 + 16*jn + r16] = f2b(oa[i][jn][rr]);
        }
      }
}

static int pick_chunks(size_t full, size_t avail) {
    for (int n = 1; n <= 8; n <<= 1) if (full / n <= avail) return n;
    return 8;   // chunked fallback (proven in R2/R6 machinery)
}

extern "C" void kernel_launch(void* const* d_in, const int* in_sizes, int n_in,
                              void* d_out, int out_size, void* d_ws, size_t ws_size,
                              hipStream_t stream)
{
    (void)in_sizes; (void)n_in; (void)out_size;
    const float* x      = (const float*)d_in[0];
    const float* n1g    = (const float*)d_in[1];
    const float* n1b    = (const float*)d_in[2];
    const float* qkv_w  = (const float*)d_in[3];
    const float* qkv_b  = (const float*)d_in[4];
    const float* rpb    = (const float*)d_in[5];
    const float* proj_w = (const float*)d_in[6];
    const float* proj_b = (const float*)d_in[7];
    const float* n2g    = (const float*)d_in[8];
    const float* n2b    = (const float*)d_in[9];
    const float* fc1_w  = (const float*)d_in[10];
    const float* fc1_b  = (const float*)d_in[11];
    const float* fc2_w  = (const float*)d_in[12];
    const float* fc2_b  = (const float*)d_in[13];
    const float* amask  = (const float*)d_in[14];
    const float* pmask  = (const float*)d_in[15];
    const int*   ridx   = (const int*)d_in[16];

    char* ws = (char*)d_ws;
    float* cm    = (float*)(ws + OFF_CM);
    u16* wqkvT   = (u16*)(ws + OFF_WQ);
    u16* wprojT  = (u16*)(ws + OFF_WP);
    u16* wfc1T   = (u16*)(ws + OFF_W1);
    u16* wfc2T   = (u16*)(ws + OFF_W2);
    u16* awin    = (u16*)(ws + OFF_AWIN);
    u16* obuf    = (u16*)(ws + OFF_OBUF);
    u16* x1b     = (u16*)(ws + OFF_X1);     // bf16 residual x1
    u16* arena   = (u16*)(ws + OFF_ARENA);  // qkv chunk, later fc1 chunk
    u16* ln2o    = (u16*)(ws + OFF_AWIN);   // reuse (awin dead after QKV)
    float* outp  = (float*)d_out;

    const size_t avail = (ws_size > OFF_ARENA) ? ws_size - OFF_ARENA : 0;

    cm_kernel  <<<dim3(64,12),  256, 0, stream>>>(amask, pmask, rpb, ridx, cm);
    wconv_kernel<<<dim3(2,1152),256, 0, stream>>>(qkv_w,  wqkvT, 384, 1152);
    wconv_kernel<<<dim3(2,384), 256, 0, stream>>>(proj_w, wprojT, 384, 384);
    wconv_kernel<<<dim3(2,1536),256, 0, stream>>>(fc1_w,  wfc1T, 384, 1536);
    wconv_kernel<<<dim3(6,384), 256, 0, stream>>>(fc2_w,  wfc2T, 1536, 384);

    ln_kernel<1><<<25088, 256, 0, stream>>>(x, n1g, n1b, awin);

    // QKV + attention; chunked only if the arena is too small
    {
        const int n_attn = pick_chunks(QKV_FULL, avail);
        const int wchunk = 2048 / n_attn;          // windows per chunk
        const int rows_a = wchunk * 49;            // 128 | rows_a for n in {1,2,4,8}
        for (int c = 0; c < n_attn; ++c) {
            const u16* aA = awin + (size_t)c*rows_a*384;
            gemm_kernel<0><<<dim3(6, rows_a/128), 256, 0, stream>>>(
                aA, wqkvT, qkv_b, arena, nullptr, rows_a, 1152, 384);
            attn_mfma2<<<wchunk*3, 256, 0, stream>>>(arena, cm, obuf, c*wchunk);
        }
    }

    gemm_kernel<1><<<dim3(2,784), 256, 0, stream>>>(obuf, wprojT, proj_b, x1b, x, 100352, 384, 384);
    ln_kernel<0><<<23296, 256, 0, stream>>>(x1b, n2g, n2b, ln2o);

    // MLP; chunked only if the arena is too small
    {
        const int n_mlp = pick_chunks(FC1_FULL, avail);
        const int rows_m = 93184 / n_mlp;          // 128 | rows_m for n in {1,2,4,8}
        for (int c = 0; c < n_mlp; ++c) {
            const size_t ro = (size_t)c*rows_m;
            gemm_kernel<2><<<dim3(8, rows_m/128), 256, 0, stream>>>(
                ln2o + ro*384, wfc1T, fc1_b, arena, nullptr, rows_m, 1536, 384);
            gemm_kernel<3><<<dim3(2, rows_m/128), 256, 0, stream>>>(
                arena, wfc2T, fc2_b, outp + ro*384, x1b + ro*384, rows_m, 384, 1536);
        }
    }
}

// Round 18
// 788.698 us; speedup vs baseline: 1.0291x; 1.0291x over previous
//
#include <hip/hip_runtime.h>
#include <hip/hip_bf16.h>

typedef unsigned short u16;
typedef short s16x8 __attribute__((ext_vector_type(8)));
typedef float f32x4 __attribute__((ext_vector_type(4)));
typedef __bf16 bf16x8 __attribute__((ext_vector_type(8)));

#define SCALE_F 0.17677669529663687f

// workspace layout (bytes). Adaptive arena; chunking absorbs small ws.
#define OFF_CM    ((size_t)0)                 // 64*12*2401*4 = 7,375,872
#define OFF_WQ    ((size_t)8<<20)             // qkvT  1152*384*2
#define OFF_WP    (OFF_WQ + 884736)           // projT 384*384*2
#define OFF_W1    (OFF_WP + 294912)           // fc1T  1536*384*2
#define OFF_W2    (OFF_W1 + 1179648)          // fc2T  384*1536*2
#define OFF_AWIN  ((size_t)12<<20)            // 77MB: A_win -> (reuse) ln2o
#define OFF_OBUF  ((size_t)90<<20)            // 73.5MB: attention output
#define OFF_X1    ((size_t)164<<20)           // 71.7MB: x1 residual (bf16)
#define OFF_ARENA ((size_t)236<<20)           // qkv chunk / fc1 chunk (adaptive)

#define QKV_FULL  ((size_t)100352*1152*2)     // 231,211,008
#define FC1_FULL  ((size_t)93184*1536*2)      // 286,261,248

static __device__ __forceinline__ u16 f2b(float f) {
    unsigned u = __float_as_uint(f);
    u += 0x7fffu + ((u >> 16) & 1u);
    return (u16)(u >> 16);
}
static __device__ __forceinline__ float b2f(u16 u) {
    return __uint_as_float((unsigned)u << 16);
}

union frag_u { s16x8 s; bf16x8 b; };
static __device__ __forceinline__ bf16x8 tob(s16x8 v) { frag_u u; u.s = v; return u.b; }

static __device__ __forceinline__ void mfma_bf16(f32x4& d, s16x8 a, s16x8 b) {
    asm("v_mfma_f32_16x16x32_bf16 %0, %1, %2, %0" : "+v"(d) : "v"(a), "v"(b));
}

static __device__ __forceinline__ void gload16(const void* g, void* l) {
    __builtin_amdgcn_global_load_lds(
        (const __attribute__((address_space(1))) unsigned int*)g,
        (__attribute__((address_space(3))) unsigned int*)l, 16, 0, 0);
}

// ---- combined mask+bias: CM[wpos][head][r*49+c] ----
__global__ void cm_kernel(const float* __restrict__ am, const float* __restrict__ pm,
                          const float* __restrict__ rpb, const int* __restrict__ ridx,
                          float* __restrict__ cmo)
{
    const int wpos = blockIdx.x, head = blockIdx.y;
    float* o = cmo + ((size_t)wpos*12 + head)*2401;
    const float* a = am + (size_t)wpos*2401;
    const float* p = pm + (size_t)wpos*2401;
    for (int e = threadIdx.x; e < 2401; e += 256)
        o[e] = a[e] + p[e] + rpb[ridx[e]*12 + head];
}

// ---- weight transpose+convert: Wt[n][k] = bf16(W[k][n]) ----
__global__ void wconv_kernel(const float* __restrict__ w, u16* __restrict__ wt,
                             int K, int N)
{
    const int k = blockIdx.x*256 + threadIdx.x;
    const int n = blockIdx.y;
    if (k < K) wt[(size_t)n*K + k] = f2b(w[(size_t)k*N + n]);
}

// ---- layernorm; WINDOWED=1: f32 in + roll/pad/window gather; 0: bf16 in ----
template<int WINDOWED>
__global__ __launch_bounds__(256, 4)
void ln_kernel(const void* __restrict__ xin, const float* __restrict__ g,
               const float* __restrict__ bt, u16* __restrict__ out)
{
    const int lane = threadIdx.x & 63;
    const int row = blockIdx.x*4 + (threadIdx.x >> 6);
    u16* orow = out + (size_t)row*384;
    float v[6];
    if (WINDOWED) {
        const float* x = (const float*)xin;
        const int win = row / 49, n = row - win*49;
        const int wpos = win & 63, b = win >> 6;
        const int n7 = n / 7;
        const int hp = (wpos >> 3)*7 + n7;
        if (hp < 4) {                 // zero-padded rows (wave-uniform)
            #pragma unroll
            for (int j=0;j<6;j++) orow[lane + 64*j] = 0;
            return;
        }
        const int wp = (wpos & 7)*7 + (n - n7*7);
        int h = hp - 1; if (h >= 52) h -= 52;   // (hp-4+3) % 52
        int w = wp + 3; if (w >= 56) w -= 56;
        const float* xr = x + (((size_t)b*52 + h)*56 + w)*384;
        #pragma unroll
        for (int j=0;j<6;j++) v[j] = xr[lane + 64*j];
    } else {
        const u16* xr = (const u16*)xin + (size_t)row*384;
        #pragma unroll
        for (int j=0;j<6;j++) v[j] = b2f(xr[lane + 64*j]);
    }
    float sum = 0.f;
    #pragma unroll
    for (int j=0;j<6;j++) sum += v[j];
    #pragma unroll
    for (int m=1;m<64;m<<=1) sum += __shfl_xor(sum, m);
    const float mean = sum * (1.f/384.f);
    float var = 0.f;
    #pragma unroll
    for (int j=0;j<6;j++){ float d = v[j]-mean; var += d*d; }
    #pragma unroll
    for (int m=1;m<64;m<<=1) var += __shfl_xor(var, m);
    const float rstd = rsqrtf(var*(1.f/384.f) + 1e-5f);
    #pragma unroll
    for (int j=0;j<6;j++){
        const int c = lane + 64*j;
        orow[c] = f2b((v[j]-mean)*rstd*g[c] + bt[c]);
    }
}

// ---- bf16 GEMM, 128x192 tile, BK=32 (R13-proven 2-phase sync + XCD swizzle) ----
// 4 waves as 2x2; each wave owns 64 rows x 96 cols (4x6 16x16 frags).
// out[M][N] = A[M][K] @ Bt[N][K]^T + bias    (N % 192 == 0)
// EPI 0: +bias -> bf16, head-blocked qkv layout [win][sel][head][49][32]
// EPI 2: tanh-GELU(+bias) -> bf16
// EPI 1: +bias +x(f32 shortcut) with inverse-window scatter -> bf16 x1
// EPI 3: +bias +x1(bf16) -> f32 d_out
template<int EPI>
__global__ __launch_bounds__(256, 2)
void gemm_kernel(const u16* __restrict__ A, const u16* __restrict__ Bt,
                 const float* __restrict__ bias, void* __restrict__ outp,
                 const void* __restrict__ extra, int M, int N, int K)
{
    (void)M;
    __shared__ u16 Als[2][4096];   // 128 rows x 32
    __shared__ u16 Bls[2][6144];   // 192 rows x 32
    const int tid = threadIdx.x;
    const int lane = tid & 63;
    const int wid = tid >> 6;
    const int wr = wid >> 1, wc = wid & 1;
    const int r16 = lane & 15, kc = lane >> 4;

    // bijective XCD swizzle: contiguous flat ranges -> one XCD (A-panel L2 reuse)
    const int gx = gridDim.x;
    const int nwg = gx * gridDim.y;
    const int flat = blockIdx.y*gx + blockIdx.x;
    const int q8 = nwg >> 3, r8 = nwg & 7;
    const int xcd = flat & 7, idx = flat >> 3;
    const int tile = (xcd < r8 ? xcd*(q8+1) : r8*(q8+1) + (xcd-r8)*q8) + idx;
    const int ty = tile / gx;
    const int m0 = ty*128, n0 = (tile - ty*gx)*192;

    const int srow = tid >> 2, schunk = tid & 3;
    const int nk = K >> 5;

    // source-chunk XOR swizzle keeps LDS dest linear but spreads banks.
    const u16* Ab = A  + (size_t)(m0 + srow)*K + (schunk ^ ((srow >> 1) & 3))*8;
    const u16* Bb = Bt + (size_t)(n0 + srow)*K + (schunk ^ ((srow >> 1) & 3))*8;
    const size_t rskip = (size_t)64*K;

    gload16(Ab,           &Als[0][tid*8]);
    gload16(Ab + rskip,   &Als[0][2048 + tid*8]);
    gload16(Bb,           &Bls[0][tid*8]);
    gload16(Bb + rskip,   &Bls[0][2048 + tid*8]);
    gload16(Bb + 2*rskip, &Bls[0][4096 + tid*8]);

    f32x4 acc[4][6] = {};
    const int swz = (kc ^ ((r16 >> 1) & 3))*8;
    for (int kt = 0; kt < nk; ++kt) {
        __syncthreads();
        if (kt + 1 < nk) {
            const int buf = (kt + 1) & 1;
            const u16* a = Ab + (kt+1)*32;
            const u16* b = Bb + (kt+1)*32;
            gload16(a,           &Als[buf][tid*8]);
            gload16(a + rskip,   &Als[buf][2048 + tid*8]);
            gload16(b,           &Bls[buf][tid*8]);
            gload16(b + rskip,   &Bls[buf][2048 + tid*8]);
            gload16(b + 2*rskip, &Bls[buf][4096 + tid*8]);
        }
        const u16* as = Als[kt & 1];
        const u16* bs = Bls[kt & 1];
        s16x8 af[4], bfr[6];
        #pragma unroll
        for (int i=0;i<4;i++)
            af[i]  = *(const s16x8*)&as[(64*wr + 16*i + r16)*32 + swz];
        #pragma unroll
        for (int j=0;j<6;j++)
            bfr[j] = *(const s16x8*)&bs[(96*wc + 16*j + r16)*32 + swz];
        #pragma unroll
        for (int i=0;i<4;i++)
            #pragma unroll
            for (int j=0;j<6;j++)
                mfma_bf16(acc[i][j], af[i], bfr[j]);
    }

    float bj[6];
    #pragma unroll
    for (int j=0;j<6;j++) bj[j] = bias[n0 + 96*wc + 16*j + r16];

    if constexpr (EPI == 0) {
        // head-blocked qkv write: [win][sel(3)][head(12)][49][32]
        u16* out = (u16*)outp;
        int colbase[6];
        #pragma unroll
        for (int j=0;j<6;j++) {
            const int col = n0 + 96*wc + 16*j + r16;
            const int sel = col/384;
            const int head = (col - sel*384) >> 5;
            colbase[j] = (sel*12 + head)*1568 + (col & 31);
        }
        #pragma unroll
        for (int i=0;i<4;i++)
          #pragma unroll
          for (int r=0;r<4;r++) {
            const int row = m0 + 64*wr + 16*i + 4*kc + r;
            const int win = row/49, r49 = row - win*49;
            u16* dst = out + (size_t)win*56448 + (size_t)r49*32;
            #pragma unroll
            for (int j=0;j<6;j++)
                dst[colbase[j]] = f2b(acc[i][j][r] + bj[j]);
          }
    } else if constexpr (EPI == 2) {
        u16* out = (u16*)outp;
        #pragma unroll
        for (int i=0;i<4;i++)
          #pragma unroll
          for (int r=0;r<4;r++) {
            const size_t row = m0 + 64*wr + 16*i + 4*kc + r;
            #pragma unroll
            for (int j=0;j<6;j++) {
                const int col = n0 + 96*wc + 16*j + r16;
                float v = acc[i][j][r] + bj[j];
                const float u2 = v*(0.79788456f + 0.035677408f*v*v);
                v = v / (1.f + __expf(-2.f*u2));
                out[row*(size_t)N + col] = f2b(v);
            }
          }
    } else if constexpr (EPI == 3) {
        float* out = (float*)outp;
        const u16* ex = (const u16*)extra;
        #pragma unroll
        for (int i=0;i<4;i++)
          #pragma unroll
          for (int r=0;r<4;r++) {
            const size_t row = m0 + 64*wr + 16*i + 4*kc + r;
            #pragma unroll
            for (int j=0;j<6;j++) {
                const int col = n0 + 96*wc + 16*j + r16;
                out[row*(size_t)N + col] = b2f(ex[row*(size_t)N + col]) + acc[i][j][r] + bj[j];
            }
          }
    } else { // EPI == 1: x1(bf16) = x(f32) + proj_out, inverse-window scatter
        u16* out = (u16*)outp;
        const float* ex = (const float*)extra;
        #pragma unroll
        for (int i=0;i<4;i++)
          #pragma unroll
          for (int r=0;r<4;r++) {
            const int row = m0 + 64*wr + 16*i + 4*kc + r;
            const int win = row / 49, n = row - win*49;
            const int wpos = win & 63, b = win >> 6;
            const int n7 = n / 7;
            const int hp = (wpos >> 3)*7 + n7;
            if (hp < 4) continue;               // dropped padded rows
            const int wp = (wpos & 7)*7 + (n - n7*7);
            int h = hp + 2; if (h >= 52) h -= 52;   // (hp-4+6) % 52
            int w = wp + 6; if (w >= 56) w -= 56;
            const size_t base = (((size_t)b*52 + h)*56 + w)*384;
            #pragma unroll
            for (int j=0;j<6;j++) {
                const int col = n0 + 96*wc + 16*j + r16;
                out[base + col] = f2b(ex[base + col] + acc[i][j][r] + bj[j]);
            }
          }
    }
}

// ---- MFMA attention v2 (R7/R9-proven) on head-blocked qkv layout ----
// qkv arena: [win][sel(3)][head(12)][49][32] bf16 — rows are 64B, dense.
// 4 blocks/CU (LDS 4x38.9KB=155.6 <= 160KB; VGPR 88 — ran correct in R15/R16).
__global__ __launch_bounds__(256, 4)
void attn_mfma2(const u16* __restrict__ qkvc, const float* __restrict__ cm,
                u16* __restrict__ o, int win_base)
{
    __shared__ float Sls[4][2432];    // 9728 B per wave
    const int tid = threadIdx.x, lane = tid & 63, wv = tid >> 6;
    const int u = blockIdx.x*4 + wv;
    const int wloc = u / 12, head = u - wloc*12;
    const int wglob = win_base + wloc;
    const int wpos = wglob & 63;
    const int r16 = lane & 15, kc = lane >> 4;
    const u16* bq = qkvc + ((size_t)(wloc*3 + 0)*12 + head)*1568;
    const u16* bk = qkvc + ((size_t)(wloc*3 + 1)*12 + head)*1568;
    const u16* bv = qkvc + ((size_t)(wloc*3 + 2)*12 + head)*1568;

    // Q,K fragments (rows padded with zeros beyond 48)
    bf16x8 qf[4], kf[4];
    #pragma unroll
    for (int i=0;i<4;i++) {
        const int row = 16*i + r16;
        s16x8 qv = {}, kv = {};
        if (row < 49) {
            qv = *(const s16x8*)&bq[row*32 + kc*8];
            kv = *(const s16x8*)&bk[row*32 + kc*8];
        }
        qf[i] = tob(qv); kf[i] = tob(kv);
    }

    // S = Q@K^T, scaled + mask, into LDS f32
    float* sw = Sls[wv];
    const float* cmb = cm + ((size_t)wpos*12 + head)*2401;
    #pragma unroll
    for (int i=0;i<4;i++)
      #pragma unroll
      for (int j=0;j<4;j++) {
        f32x4 s = {};
        s = __builtin_amdgcn_mfma_f32_16x16x32_bf16(qf[i], kf[j], s, 0, 0, 0);
        #pragma unroll
        for (int r=0;r<4;r++) {
            const int row = 16*i + 4*kc + r;
            const int col = 16*j + r16;
            if (row < 49 && col < 49)
                sw[row*49 + col] = s[r]*SCALE_F + cmb[row*49 + col];
        }
      }
    __syncthreads();

    // softmax: proven scalar pattern — lane r owns row r, all fp32
    float e[49]; float inv = 0.f;
    const int r = lane;
    if (r < 49) {
        #pragma unroll
        for (int c=0;c<49;c++) e[c] = sw[r*49 + c];
        float mx = -1e30f;
        #pragma unroll
        for (int c=0;c<49;c++) mx = fmaxf(mx, e[c]);
        float sm = 0.f;
        #pragma unroll
        for (int c=0;c<49;c++){ e[c] = __expf(e[c]-mx); sm += e[c]; }
        inv = 1.f/sm;
    }
    __syncthreads();   // all S reads complete before the P overlay is written

    // P (bf16, stride 72, cols 49..63 zeroed) overlays the S region
    u16* pw = (u16*)sw;
    if (r < 49) {
        #pragma unroll
        for (int w8 = 0; w8 < 8; ++w8) {
            s16x8 pk = {};
            #pragma unroll
            for (int jj=0;jj<8;jj++) {
                const int c = w8*8 + jj;
                if (c < 49) pk[jj] = (short)f2b(e[c]*inv);
            }
            *(s16x8*)&pw[r*72 + w8*8] = pk;
        }
    }
    __syncthreads();

    // V in B-fragment layout (k>48 clamped to row 0; multiplied by P==0)
    bf16x8 vf[2][2];
    #pragma unroll
    for (int kk=0;kk<2;kk++)
      #pragma unroll
      for (int jn=0;jn<2;jn++) {
        s16x8 vv;
        #pragma unroll
        for (int jj=0;jj<8;jj++) {
            int k = 32*kk + 8*kc + jj;
            if (k > 48) k = 0;
            vv[jj] = (short)bv[k*32 + 16*jn + r16];
        }
        vf[kk][jn] = tob(vv);
      }

    // O = P @ V
    f32x4 oa[4][2] = {};
    #pragma unroll
    for (int i=0;i<4;i++)
      #pragma unroll
      for (int kk=0;kk<2;kk++) {
        const bf16x8 pa = tob(*(const s16x8*)&pw[(16*i + r16)*72 + 32*kk + kc*8]);
        #pragma unroll
        for (int jn=0;jn<2;jn++)
            oa[i][jn] = __builtin_amdgcn_mfma_f32_16x16x32_bf16(pa, vf[kk][jn], oa[i][jn], 0, 0, 0);
      }

    #pragma unroll
    for (int i=0;i<4;i++)
      #pragma unroll
      for (int rr=0;rr<4;rr++) {
        const int row = 16*i + 4*kc + rr;
        if (row < 49) {
          #pragma unroll
          for (int jn=0;jn<2;jn++)
            o[(size_t)(wglob*49 + row)*384 + head*32 + 16*jn + r16] = f2b(oa[i][jn][rr]);
        }
      }
}

static int pick_chunks(size_t full, size_t avail) {
    for (int n = 1; n <= 8; n <<= 1) if (full / n <= avail) return n;
    return 8;   // chunked fallback (proven in R2/R6 machinery)
}

extern "C" void kernel_launch(void* const* d_in, const int* in_sizes, int n_in,
                              void* d_out, int out_size, void* d_ws, size_t ws_size,
                              hipStream_t stream)
{
    (void)in_sizes; (void)n_in; (void)out_size;
    const float* x      = (const float*)d_in[0];
    const float* n1g    = (const float*)d_in[1];
    const float* n1b    = (const float*)d_in[2];
    const float* qkv_w  = (const float*)d_in[3];
    const float* qkv_b  = (const float*)d_in[4];
    const float* rpb    = (const float*)d_in[5];
    const float* proj_w = (const float*)d_in[6];
    const float* proj_b = (const float*)d_in[7];
    const float* n2g    = (const float*)d_in[8];
    const float* n2b    = (const float*)d_in[9];
    const float* fc1_w  = (const float*)d_in[10];
    const float* fc1_b  = (const float*)d_in[11];
    const float* fc2_w  = (const float*)d_in[12];
    const float* fc2_b  = (const float*)d_in[13];
    const float* amask  = (const float*)d_in[14];
    const float* pmask  = (const float*)d_in[15];
    const int*   ridx   = (const int*)d_in[16];

    char* ws = (char*)d_ws;
    float* cm    = (float*)(ws + OFF_CM);
    u16* wqkvT   = (u16*)(ws + OFF_WQ);
    u16* wprojT  = (u16*)(ws + OFF_WP);
    u16* wfc1T   = (u16*)(ws + OFF_W1);
    u16* wfc2T   = (u16*)(ws + OFF_W2);
    u16* awin    = (u16*)(ws + OFF_AWIN);
    u16* obuf    = (u16*)(ws + OFF_OBUF);
    u16* x1b     = (u16*)(ws + OFF_X1);     // bf16 residual x1
    u16* arena   = (u16*)(ws + OFF_ARENA);  // qkv chunk, later fc1 chunk
    u16* ln2o    = (u16*)(ws + OFF_AWIN);   // reuse (awin dead after QKV)
    float* outp  = (float*)d_out;

    const size_t avail = (ws_size > OFF_ARENA) ? ws_size - OFF_ARENA : 0;

    cm_kernel  <<<dim3(64,12),  256, 0, stream>>>(amask, pmask, rpb, ridx, cm);
    wconv_kernel<<<dim3(2,1152),256, 0, stream>>>(qkv_w,  wqkvT, 384, 1152);
    wconv_kernel<<<dim3(2,384), 256, 0, stream>>>(proj_w, wprojT, 384, 384);
    wconv_kernel<<<dim3(2,1536),256, 0, stream>>>(fc1_w,  wfc1T, 384, 1536);
    wconv_kernel<<<dim3(6,384), 256, 0, stream>>>(fc2_w,  wfc2T, 1536, 384);

    ln_kernel<1><<<25088, 256, 0, stream>>>(x, n1g, n1b, awin);

    // QKV + attention; chunked only if the arena is too small
    {
        const int n_attn = pick_chunks(QKV_FULL, avail);
        const int wchunk = 2048 / n_attn;          // windows per chunk
        const int rows_a = wchunk * 49;            // 128 | rows_a for n in {1,2,4,8}
        for (int c = 0; c < n_attn; ++c) {
            const u16* aA = awin + (size_t)c*rows_a*384;
            gemm_kernel<0><<<dim3(6, rows_a/128), 256, 0, stream>>>(
                aA, wqkvT, qkv_b, arena, nullptr, rows_a, 1152, 384);
            attn_mfma2<<<wchunk*3, 256, 0, stream>>>(arena, cm, obuf, c*wchunk);
        }
    }

    gemm_kernel<1><<<dim3(2,784), 256, 0, stream>>>(obuf, wprojT, proj_b, x1b, x, 100352, 384, 384);
    ln_kernel<0><<<23296, 256, 0, stream>>>(x1b, n2g, n2b, ln2o);

    // MLP; chunked only if the arena is too small
    {
        const int n_mlp = pick_chunks(FC1_FULL, avail);
        const int rows_m = 93184 / n_mlp;          // 128 | rows_m for n in {1,2,4,8}
        for (int c = 0; c < n_mlp; ++c) {
            const size_t ro = (size_t)c*rows_m;
            gemm_kernel<2><<<dim3(8, rows_m/128), 256, 0, stream>>>(
                ln2o + ro*384, wfc1T, fc1_b, arena, nullptr, rows_m, 1536, 384);
            gemm_kernel<3><<<dim3(2, rows_m/128), 256, 0, stream>>>(
                arena, wfc2T, fc2_b, outp + ro*384, x1b + ro*384, rows_m, 384, 1536);
        }
    }
}